// Round 1
// 442.663 us; speedup vs baseline: 1.0488x; 1.0488x over previous
//
#include <hip/hip_runtime.h>

#define N_NODES 100000
#define N_EDGES 1600000
#define IN_DIM 160
#define HID 128
#define BN_EPS 1e-5f

#define M_PAD 100096   // 1564 * 64 rows (GEMM block = 64 rows)
#define NBUCK 196      // 512-node buckets (196*512 = 100352 >= N_NODES)
#define BSH 9
#define EPB 8192       // edges per block in hist/scatter kernels
#define NHB (NBUCK * NBUCK)   // 38416, divisible by 4
#define NSB 38         // scan blocks: 38*1024 = 38912 >= NHB
#define LPAD 132       // gemm LDS repack row stride (ushorts)
#define NSLOT (NBUCK * 512)   // 100352 perm slots

typedef unsigned int uint;
typedef unsigned short ushort;
typedef __attribute__((ext_vector_type(8))) short bf16x8;
typedef __attribute__((ext_vector_type(4))) float f32x4;
typedef __attribute__((ext_vector_type(2))) float f32x2;

__device__ __forceinline__ ushort bf16rn(float f) {
    uint u = __float_as_uint(f);
    u += 0x7fffu + ((u >> 16) & 1u);
    return (ushort)(u >> 16);
}
__device__ __forceinline__ float bflo(uint u) { return __uint_as_float(u << 16); }
__device__ __forceinline__ float bfhi(uint u) { return __uint_as_float(u & 0xffff0000u); }

// ---------------------------------------------------------------------------
// Fused init: hist (196 blocks) + weight prep (52 blocks) + bn prep (2) +
// h pad-row zeroing (1). All independent work before the scan chain.
// ---------------------------------------------------------------------------

__device__ __forceinline__ void prep_body(int ob, int lane, const float* __restrict__ wl,
                                          const float* __restrict__ wr,
                                          ushort* __restrict__ Bf, int K) {
    int kb = ob >> 4;       // K-step (32 wide)
    int tt = ob & 15;       // col tile
    int n = tt * 16 + (lane & 15);
    int k0 = kb * 32 + (lane >> 4) * 8;
    ushort* dst = Bf + ((size_t)(kb * 16 + tt) * 64 + lane) * 8;
#pragma unroll
    for (int e = 0; e < 8; ++e) {
        int k = k0 + e;
        float v = (n < HID) ? wl[k * HID + n] : wr[k * HID + (n - HID)];
        dst[e] = bf16rn(v);
    }
}

#define PREP0_B 20   // (IN_DIM/32)*16 = 80 old 64-thread blocks / 4
#define PREP1_B 16   // (HID/32)*16   = 64 old 64-thread blocks / 4
#define INIT_GRID (NBUCK + PREP0_B + 2 * PREP1_B + 2 + 1)

__global__ __launch_bounds__(256) void init_kernel(
    const int* __restrict__ dst, int* __restrict__ ghist,
    const float* __restrict__ wl0, const float* __restrict__ wr0,
    const float* __restrict__ wl1, const float* __restrict__ wr1,
    const float* __restrict__ wl2, const float* __restrict__ wr2,
    ushort* __restrict__ Bf0, ushort* __restrict__ Bf1, ushort* __restrict__ Bf2,
    const float* __restrict__ bl0, const float* __restrict__ g0,
    const float* __restrict__ be0, const float* __restrict__ rm0,
    const float* __restrict__ rv0,
    const float* __restrict__ bl1, const float* __restrict__ g1,
    const float* __restrict__ be1, const float* __restrict__ rm1,
    const float* __restrict__ rv1,
    const float* __restrict__ bl2, const float* __restrict__ g2,
    const float* __restrict__ be2, const float* __restrict__ rm2,
    const float* __restrict__ rv2,
    float* __restrict__ bnscale, float* __restrict__ bnshift,
    ushort* __restrict__ h) {
    __shared__ int hist[NBUCK];
    int b = blockIdx.x, t = threadIdx.x;
    if (b < NBUCK) {
        for (int i = t; i < NBUCK; i += 256) hist[i] = 0;
        __syncthreads();
        int e0 = b * EPB;
        for (int i = 0; i < EPB; i += 256) {
            int e = e0 + i + t;
            if (e < N_EDGES) atomicAdd(&hist[dst[e] >> BSH], 1);
        }
        __syncthreads();
        for (int i = t; i < NBUCK; i += 256) ghist[i * NBUCK + b] = hist[i];
    } else if (b < NBUCK + PREP0_B) {
        int ob = (b - NBUCK) * 4 + (t >> 6);
        prep_body(ob, t & 63, wl0, wr0, Bf0, IN_DIM);
    } else if (b < NBUCK + PREP0_B + PREP1_B) {
        int ob = (b - NBUCK - PREP0_B) * 4 + (t >> 6);
        prep_body(ob, t & 63, wl1, wr1, Bf1, HID);
    } else if (b < NBUCK + PREP0_B + 2 * PREP1_B) {
        int ob = (b - NBUCK - PREP0_B - PREP1_B) * 4 + (t >> 6);
        prep_body(ob, t & 63, wl2, wr2, Bf2, HID);
    } else if (b < NBUCK + PREP0_B + 2 * PREP1_B + 2) {
        int tt = (b - (NBUCK + PREP0_B + 2 * PREP1_B)) * 256 + t;
        if (tt < 3 * HID) {
            int L = tt >> 7, j = tt & 127;
            const float* bl = (L == 0) ? bl0 : (L == 1) ? bl1 : bl2;
            const float* gg = (L == 0) ? g0  : (L == 1) ? g1  : g2;
            const float* be = (L == 0) ? be0 : (L == 1) ? be1 : be2;
            const float* rm = (L == 0) ? rm0 : (L == 1) ? rm1 : rm2;
            const float* rv = (L == 0) ? rv0 : (L == 1) ? rv1 : rv2;
            float s = gg[j] * rsqrtf(rv[j] + BN_EPS);
            bnscale[tt] = s;
            bnshift[tt] = (bl[j] - rm[j]) * s + be[j];
        }
    } else {
        // zero h pad rows once; agg never writes pad rows, gemm only reads h
        uint* hp = (uint*)(h + (size_t)N_NODES * HID);
        for (int i = t; i < (M_PAD - N_NODES) * HID / 2; i += 256) hp[i] = 0u;
    }
}

// ---------------------------------------------------------------------------
// Scan chain (unchanged)
// ---------------------------------------------------------------------------

__global__ __launch_bounds__(256) void scan1_kernel(const int* __restrict__ ghist,
                                                    int* __restrict__ bsum) {
    __shared__ int wsum[4];
    int b = blockIdx.x, t = threadIdx.x;
    int i4 = b * 256 + t;
    int4 v = (i4 * 4 < NHB) ? ((const int4*)ghist)[i4] : make_int4(0, 0, 0, 0);
    int s = v.x + v.y + v.z + v.w;
#pragma unroll
    for (int off = 32; off; off >>= 1) s += __shfl_down(s, off);
    if ((t & 63) == 0) wsum[t >> 6] = s;
    __syncthreads();
    if (t == 0) bsum[b] = wsum[0] + wsum[1] + wsum[2] + wsum[3];
}

__global__ void scan2_kernel(const int* __restrict__ bsum, int* __restrict__ boff,
                             int* __restrict__ gbb) {
    int lane = threadIdx.x;
    int v = (lane < NSB) ? bsum[lane] : 0;
    int s = v;
#pragma unroll
    for (int off = 1; off <= 32; off <<= 1) {
        int t2 = __shfl_up(s, off);
        if (lane >= off) s += t2;
    }
    if (lane < NSB) boff[lane] = s - v;
    if (lane == 0) gbb[NBUCK] = N_EDGES;
}

__global__ __launch_bounds__(256) void scan3_kernel(int* __restrict__ ghist,
                                                    const int* __restrict__ boff,
                                                    int* __restrict__ gbb) {
    __shared__ int ts[256];
    int b = blockIdx.x, t = threadIdx.x;
    int i4 = b * 256 + t;
    bool ok = (i4 * 4) < NHB;
    int4 v = ok ? ((const int4*)ghist)[i4] : make_int4(0, 0, 0, 0);
    int s = v.x + v.y + v.z + v.w;
    ts[t] = s;
    __syncthreads();
    for (int off = 1; off < 256; off <<= 1) {
        int a = (t >= off) ? ts[t - off] : 0;
        __syncthreads();
        ts[t] += a;
        __syncthreads();
    }
    int excl = boff[b] + ((t > 0) ? ts[t - 1] : 0);
    if (ok) {
        int idx = i4 * 4;
        int4 w;
        w.x = excl;
        w.y = excl + v.x;
        w.z = excl + v.x + v.y;
        w.w = excl + v.x + v.y + v.z;
        ((int4*)ghist)[i4] = w;
        if (idx % NBUCK == 0) gbb[idx / NBUCK] = w.x;
    }
}

// ---------------------------------------------------------------------------
// Bucket CSR (adds per-bucket class-sorted node permutation, class=ceil(deg/16))
// ---------------------------------------------------------------------------

__global__ __launch_bounds__(256) void bucket_csr_kernel(const uint* __restrict__ scat,
                                                         const int* __restrict__ gbb,
                                                         int* __restrict__ prow,
                                                         int* __restrict__ deg,
                                                         int* __restrict__ peidx,
                                                         int* __restrict__ perm) {
    __shared__ int cnt[512], fl[512], pref[512];
    __shared__ int ts[256];
    __shared__ int tot_s;
    __shared__ int clsCnt[8], clsFill[8], clsBase[9];
    int b = blockIdx.x, t = threadIdx.x;
    int beg = gbb[b], end = gbb[b + 1];
    int pb = beg + b * 8192;
    cnt[t] = 0; cnt[t + 256] = 0;
    if (t < 8) { clsCnt[t] = 0; clsFill[t] = 0; }
    __syncthreads();
    for (int i = beg + t; i < end; i += 256)
        atomicAdd(&cnt[scat[i] >> 17], 1);
    __syncthreads();
    int c0 = cnt[2 * t], c1 = cnt[2 * t + 1];
    int g0 = b * 512 + 2 * t;
    // batch-count classes for load-balanced agg waves
    int cls0 = (c0 == 0) ? 0 : ((c0 + 15) >> 4); if (cls0 > 7) cls0 = 7;
    int cls1 = (c1 == 0) ? 0 : ((c1 + 15) >> 4); if (cls1 > 7) cls1 = 7;
    if (g0 < N_NODES) atomicAdd(&clsCnt[cls0], 1);
    if (g0 + 1 < N_NODES) atomicAdd(&clsCnt[cls1], 1);
    int p0 = (c0 + 15) & ~15, p1 = (c1 + 15) & ~15;
    ts[t] = p0 + p1;
    __syncthreads();
    for (int off = 1; off < 256; off <<= 1) {
        int v = (t >= off) ? ts[t - off] : 0;
        __syncthreads();
        ts[t] += v;
        __syncthreads();
    }
    int ex = (t > 0) ? ts[t - 1] : 0;
    pref[2 * t] = ex;
    pref[2 * t + 1] = ex + p0;
    fl[t] = 0; fl[t + 256] = 0;
    if (t == 255) tot_s = ts[255];
    if (g0 < N_NODES) { prow[g0] = pb + ex; deg[g0] = c0; }
    if (g0 + 1 < N_NODES) { prow[g0 + 1] = pb + ex + p0; deg[g0 + 1] = c1; }
    __syncthreads();
    if (t == 0) {
        int sacc = 0;
#pragma unroll
        for (int i = 0; i < 8; ++i) { clsBase[i] = sacc; sacc += clsCnt[i]; }
        clsBase[8] = sacc;
    }
    __syncthreads();
    // class-sorted perm (order within class arbitrary)
    if (g0 < N_NODES) {
        int p = atomicAdd(&clsFill[cls0], 1);
        perm[b * 512 + clsBase[cls0] + p] = g0;
    }
    if (g0 + 1 < N_NODES) {
        int p = atomicAdd(&clsFill[cls1], 1);
        perm[b * 512 + clsBase[cls1] + p] = g0 + 1;
    }
    int vt = clsBase[8];
    for (int i = vt + t; i < 512; i += 256) perm[b * 512 + i] = N_NODES;  // invalid marker
    int tot = tot_s;
    for (int i = t; i < tot; i += 256) peidx[pb + i] = N_NODES;  // pad -> zero row
    __syncthreads();
    for (int i = beg + t; i < end; i += 256) {
        uint w = scat[i];
        int nl = (int)(w >> 17);
        int lp = atomicAdd(&fl[nl], 1);
        peidx[pb + pref[nl] + lp] = (int)(w & 0x1FFFFu);
    }
}

// ---------------------------------------------------------------------------
// GEMM body: [tl | troot] = A @ [wl | wr]. Block = 64 rows x 256 cols.
// ---------------------------------------------------------------------------
template <int K, bool AFP32>
__device__ __forceinline__ void gemm_body(int bx, int t, ushort* ldsA,
                                          const void* __restrict__ A_,
                                          const ushort* __restrict__ Bf,
                                          ushort* __restrict__ tl,
                                          ushort* __restrict__ troot) {
    constexpr int CPR = K / 8;                 // 16B chunks per row
    constexpr int FULLG = CPR & ~7;            // start of partial swizzle group
    const int m0b = bx * 64;

    // ---- Stage A tile (64 rows x K) ----
#pragma unroll
    for (int i = 0; i < (64 * CPR) / 256; ++i) {
        int cidx = i * 256 + t;
        int row = cidx / CPR;
        int j = cidx - row * CPR;
        bf16x8 v;
        if (AFP32) {
            const float* A = (const float*)A_;
            int m = m0b + row;
            float4 f0 = make_float4(0.f, 0.f, 0.f, 0.f), f1 = f0;
            if (m < N_NODES) {
                f0 = *(const float4*)(A + (size_t)m * K + j * 8);
                f1 = *(const float4*)(A + (size_t)m * K + j * 8 + 4);
            }
            v[0] = (short)bf16rn(f0.x); v[1] = (short)bf16rn(f0.y);
            v[2] = (short)bf16rn(f0.z); v[3] = (short)bf16rn(f0.w);
            v[4] = (short)bf16rn(f1.x); v[5] = (short)bf16rn(f1.y);
            v[6] = (short)bf16rn(f1.z); v[7] = (short)bf16rn(f1.w);
        } else {
            const ushort* A = (const ushort*)A_;
            v = *(const bf16x8*)(A + (size_t)(m0b + row) * K + j * 8);
        }
        int swz = (j < FULLG) ? ((j & ~7) | ((j ^ row) & 7))
                              : ((j & ~3) | ((j ^ row) & 3));
        *(bf16x8*)&ldsA[row * K + swz * 8] = v;
    }
    __syncthreads();

    // ---- K-loop ----
    const int lane = t & 63;
    const int wv = t >> 6;
    const int col = lane & 15;
    const int q = lane >> 4;
    const int rh = wv & 1;
    const int ch = wv >> 1;
    const int row0 = rh * 32 + col;            // row0 & 7 == col & 7
    f32x4 acc0[8], acc1[8];
#pragma unroll
    for (int tt = 0; tt < 8; ++tt) {
        acc0[tt] = (f32x4){0.f, 0.f, 0.f, 0.f};
        acc1[tt] = (f32x4){0.f, 0.f, 0.f, 0.f};
    }

#pragma unroll
    for (int kb = 0; kb < K / 32; ++kb) {
        int jj = kb * 4 + q;
        int swzj = (jj < FULLG) ? ((jj & ~7) | ((jj ^ col) & 7))
                                : ((jj & ~3) | ((jj ^ col) & 3));
        bf16x8 a0 = *(const bf16x8*)&ldsA[row0 * K + swzj * 8];
        bf16x8 a1 = *(const bf16x8*)&ldsA[(row0 + 16) * K + swzj * 8];
        const ushort* bp = Bf + ((size_t)((kb * 16 + ch * 8) * 64) + lane) * 8;
#pragma unroll
        for (int tt = 0; tt < 8; ++tt) {
            bf16x8 bfr = *(const bf16x8*)(bp + (size_t)tt * 64 * 8);
            acc0[tt] = __builtin_amdgcn_mfma_f32_16x16x32_bf16(a0, bfr, acc0[tt], 0, 0, 0);
            acc1[tt] = __builtin_amdgcn_mfma_f32_16x16x32_bf16(a1, bfr, acc1[tt], 0, 0, 0);
        }
    }

    // ---- Epilogue: per-wave LDS repack (128 cols), coalesced 256B stores ----
    __syncthreads();   // all waves done reading A region before aliasing
    ushort(*rp)[16][LPAD] = (ushort(*)[16][LPAD])ldsA;
    ushort* outp = ch ? troot : tl;
#pragma unroll
    for (int mt = 0; mt < 2; ++mt) {
        const f32x4* ac = mt ? acc1 : acc0;
#pragma unroll
        for (int tt = 0; tt < 8; ++tt)
#pragma unroll
            for (int r = 0; r < 4; ++r)
                rp[wv][q * 4 + r][tt * 16 + col] = bf16rn(ac[tt][r]);
        int mbase = m0b + rh * 32 + mt * 16;
#pragma unroll
        for (int i = 0; i < 4; ++i) {
            int lin = i * 64 + lane;
            int row = lin >> 4;      // 4 rows per instr (16 lanes x 16B)
            int c16 = lin & 15;
            bf16x8 v = *(const bf16x8*)&rp[wv][row][c16 * 8];
            *(bf16x8*)(outp + (size_t)(mbase + row) * HID + c16 * 8) = v;
        }
    }
}

template <int K, bool AFP32>
__global__ __launch_bounds__(256) void gemm_kernel(const void* __restrict__ A_,
                                                   const ushort* __restrict__ Bf,
                                                   ushort* __restrict__ tl,
                                                   ushort* __restrict__ troot) {
    constexpr int LDSE = (64 * K > 4 * 16 * LPAD) ? 64 * K : 4 * 16 * LPAD;
    __shared__ ushort ldsA[LDSE];
    gemm_body<K, AFP32>(blockIdx.x, threadIdx.x, ldsA, A_, Bf, tl, troot);
}

// ---------------------------------------------------------------------------
// Fused scatter (196 latency-bound blocks) + layer-0 GEMM (1564 compute blocks).
// Independent work; overlapping hides the scatter behind the GEMM.
// ---------------------------------------------------------------------------
__global__ __launch_bounds__(256) void scatter_gemm1_kernel(
    const int* __restrict__ src, const int* __restrict__ dst,
    const int* __restrict__ ghist, uint* __restrict__ scat,
    const float* __restrict__ x, const ushort* __restrict__ Bf0,
    ushort* __restrict__ tl, ushort* __restrict__ troot) {
    constexpr int LDSE = (64 * IN_DIM > 4 * 16 * LPAD) ? 64 * IN_DIM : 4 * 16 * LPAD;
    __shared__ ushort ldsA[LDSE];
    int b = blockIdx.x, t = threadIdx.x;
    if (b < NBUCK) {
        int* base = (int*)ldsA;
        int* fill = base + NBUCK;
        for (int i = t; i < NBUCK; i += 256) { base[i] = ghist[i * NBUCK + b]; fill[i] = 0; }
        __syncthreads();
        int e0 = b * EPB;
        for (int i = 0; i < EPB; i += 256) {
            int e = e0 + i + t;
            if (e < N_EDGES) {
                int d = dst[e];
                int sv = src[e];
                int bk = d >> BSH;
                int lp = atomicAdd(&fill[bk], 1);
                scat[base[bk] + lp] = (uint)sv | ((uint)(d & 511) << 17);
            }
        }
    } else {
        gemm_body<IN_DIM, true>(b - NBUCK, t, ldsA, x, Bf0, tl, troot);
    }
}

// ---------------------------------------------------------------------------
// Aggregation + BN + ReLU (+ fused final linear).
// Wave = 4 nodes via class-sorted perm (nodes with equal batch count share a
// wave -> no max-over-4 imbalance). 2-deep pipeline: next batch's indices
// prefetched before consuming current gathered rows.
// ---------------------------------------------------------------------------
template <bool FINAL>
__global__ __launch_bounds__(256) void agg_kernel(
    const ushort* __restrict__ tl_, const ushort* __restrict__ troot_,
    const int* __restrict__ prow, const int* __restrict__ deg_,
    const int* __restrict__ peidx, const int* __restrict__ perm,
    const float* __restrict__ bnscale, const float* __restrict__ bnshift,
    const float* __restrict__ linw, const float* __restrict__ linb,
    ushort* __restrict__ hout, float* __restrict__ out) {
    const int lane = threadIdx.x & 63;
    const int wvg = (blockIdx.x * 256 + (int)threadIdx.x) >> 6;
    const int g = lane >> 4;          // group 0..3 -> node slot
    const int s = lane & 15;          // feat slice: feats s*8 .. s*8+7
    const int slot = wvg * 4 + g;     // < NSLOT by grid construction
    const int n = perm[slot];         // node id, or N_NODES marker
    const bool valid = (n < N_NODES);
    const int nn = valid ? n : 0;

    float4 sc0 = *(const float4*)(bnscale + s * 8);
    float4 sc1 = *(const float4*)(bnscale + s * 8 + 4);
    float4 sh0 = *(const float4*)(bnshift + s * 8);
    float4 sh1 = *(const float4*)(bnshift + s * 8 + 4);

    int pbeg = prow[nn];
    int dg = valid ? deg_[nn] : 0;
    int myb = (dg + 15) >> 4;         // batches of 16 edges

    f32x2 acc2[4];
#pragma unroll
    for (int i = 0; i < 4; ++i) acc2[i] = (f32x2){0.f, 0.f};

    const int gsel = (lane & 48) << 2;   // bpermute byte-addr base of my group

    bool act = (0 < myb);
    int idx = act ? peidx[pbeg + s] : N_NODES;
    int b = 0;
    while (__any(act)) {
        uint4 u[16];
#pragma unroll
        for (int jj = 0; jj < 16; ++jj) {
            int srcj = __builtin_amdgcn_ds_bpermute(gsel | (jj << 2), idx);
            u[jj] = *(const uint4*)(tl_ + (size_t)srcj * HID + s * 8);
        }
        ++b;
        bool actn = (b < myb);
        int idxn = actn ? peidx[pbeg + b * 16 + s] : N_NODES;  // prefetch next batch
#pragma unroll
        for (int jj = 0; jj < 16; ++jj) {
            acc2[0] += (f32x2){bflo(u[jj].x), bfhi(u[jj].x)};
            acc2[1] += (f32x2){bflo(u[jj].y), bfhi(u[jj].y)};
            acc2[2] += (f32x2){bflo(u[jj].z), bfhi(u[jj].z)};
            acc2[3] += (f32x2){bflo(u[jj].w), bfhi(u[jj].w)};
        }
        act = actn; idx = idxn;
    }

    float inv = 1.0f / (float)((dg > 0) ? dg : 1);
    uint4 rv = *(const uint4*)(troot_ + (size_t)nn * HID + s * 8);
    float o[8];
    o[0] = fmaxf(fmaf(fmaf(acc2[0].x, inv, bflo(rv.x)), sc0.x, sh0.x), 0.f);
    o[1] = fmaxf(fmaf(fmaf(acc2[0].y, inv, bfhi(rv.x)), sc0.y, sh0.y), 0.f);
    o[2] = fmaxf(fmaf(fmaf(acc2[1].x, inv, bflo(rv.y)), sc0.z, sh0.z), 0.f);
    o[3] = fmaxf(fmaf(fmaf(acc2[1].y, inv, bfhi(rv.y)), sc0.w, sh0.w), 0.f);
    o[4] = fmaxf(fmaf(fmaf(acc2[2].x, inv, bflo(rv.z)), sc1.x, sh1.x), 0.f);
    o[5] = fmaxf(fmaf(fmaf(acc2[2].y, inv, bfhi(rv.z)), sc1.y, sh1.y), 0.f);
    o[6] = fmaxf(fmaf(fmaf(acc2[3].x, inv, bflo(rv.w)), sc1.z, sh1.z), 0.f);
    o[7] = fmaxf(fmaf(fmaf(acc2[3].y, inv, bfhi(rv.w)), sc1.w, sh1.w), 0.f);

    if (FINAL) {
        float4 w0 = *(const float4*)(linw + s * 8);
        float4 w1 = *(const float4*)(linw + s * 8 + 4);
        float p = o[0] * w0.x + o[1] * w0.y + o[2] * w0.z + o[3] * w0.w +
                  o[4] * w1.x + o[5] * w1.y + o[6] * w1.z + o[7] * w1.w;
#pragma unroll
        for (int off = 1; off < 16; off <<= 1) p += __shfl_xor(p, off);
        if (s == 0 && valid) out[n] = p + linb[0];
    } else {
        if (valid) {
            uint4 pk;
            pk.x = (uint)bf16rn(o[0]) | ((uint)bf16rn(o[1]) << 16);
            pk.y = (uint)bf16rn(o[2]) | ((uint)bf16rn(o[3]) << 16);
            pk.z = (uint)bf16rn(o[4]) | ((uint)bf16rn(o[5]) << 16);
            pk.w = (uint)bf16rn(o[6]) | ((uint)bf16rn(o[7]) << 16);
            *(uint4*)(hout + (size_t)n * HID + s * 8) = pk;
        }
    }
}

// ---------------------------------------------------------------------------

extern "C" void kernel_launch(void* const* d_in, const int* in_sizes, int n_in,
                              void* d_out, int out_size, void* d_ws, size_t ws_size,
                              hipStream_t stream) {
    const float* x    = (const float*)d_in[0];
    const int*   ei   = (const int*)d_in[1];
    const int*   esrc = ei;
    const int*   edst = ei + N_EDGES;
    const float* wl[3]; const float* wr[3]; const float* bl[3];
    const float* g[3];  const float* be[3]; const float* rm[3]; const float* rv[3];
    for (int i = 0; i < 3; ++i) {
        wl[i] = (const float*)d_in[2 + 7 * i];
        wr[i] = (const float*)d_in[3 + 7 * i];
        bl[i] = (const float*)d_in[4 + 7 * i];
        g[i]  = (const float*)d_in[5 + 7 * i];
        be[i] = (const float*)d_in[6 + 7 * i];
        rm[i] = (const float*)d_in[7 + 7 * i];
        rv[i] = (const float*)d_in[8 + 7 * i];
    }
    const float* lin_w = (const float*)d_in[23];
    const float* lin_b = (const float*)d_in[24];
    float* out = (float*)d_out;

    // Workspace carve-up (~98 MB total).
    char* ws = (char*)d_ws;
    size_t off = 0;
    auto carve = [&](size_t bytes) -> void* {
        void* p = ws + off;
        off += (bytes + 255) & ~(size_t)255;
        return p;
    };
    int*    prow   = (int*)carve((size_t)(N_NODES + 8) * sizeof(int));
    int*    deg    = (int*)carve((size_t)(N_NODES + 8) * sizeof(int));
    int*    peidx  = (int*)carve((size_t)3210000 * sizeof(int));   // padded CSR
    uint*   scat   = (uint*)carve((size_t)N_EDGES * sizeof(uint));
    int*    ghist  = (int*)carve((size_t)(NSB * 1024) * sizeof(int));
    int*    gbb    = (int*)carve((NBUCK + 4) * sizeof(int));
    int*    bsum   = (int*)carve((NSB + 2) * sizeof(int));
    int*    boff   = (int*)carve((NSB + 2) * sizeof(int));
    int*    perm   = (int*)carve((size_t)NSLOT * sizeof(int));
    ushort* tl     = (ushort*)carve((size_t)(M_PAD + 1) * HID * sizeof(ushort));
    ushort* troot  = (ushort*)carve((size_t)M_PAD * HID * sizeof(ushort));
    ushort* h      = (ushort*)carve((size_t)M_PAD * HID * sizeof(ushort));
    ushort* Bf0    = (ushort*)carve(256 * IN_DIM * sizeof(ushort));
    ushort* Bf1    = (ushort*)carve(256 * HID * sizeof(ushort));
    ushort* Bf2    = (ushort*)carve(256 * HID * sizeof(ushort));
    float*  bnsc   = (float*)carve(3 * HID * sizeof(float));
    float*  bnsh   = (float*)carve(3 * HID * sizeof(float));
    (void)ws_size; (void)n_in; (void)in_sizes; (void)out_size;

    const int GEMM_GRID = M_PAD / 64;           // 1564 blocks, 64 rows x 256 cols
    const int AGG_GRID = NSLOT / 16;            // 6272: 16 perm slots per block

    init_kernel<<<INIT_GRID, 256, 0, stream>>>(
        edst, ghist,
        wl[0], wr[0], wl[1], wr[1], wl[2], wr[2], Bf0, Bf1, Bf2,
        bl[0], g[0], be[0], rm[0], rv[0],
        bl[1], g[1], be[1], rm[1], rv[1],
        bl[2], g[2], be[2], rm[2], rv[2],
        bnsc, bnsh, h);
    scan1_kernel<<<NSB, 256, 0, stream>>>(ghist, bsum);
    scan2_kernel<<<1, 64, 0, stream>>>(bsum, boff, gbb);
    scan3_kernel<<<NSB, 256, 0, stream>>>(ghist, boff, gbb);
    scatter_gemm1_kernel<<<NBUCK + GEMM_GRID, 256, 0, stream>>>(
        esrc, edst, ghist, scat, x, Bf0, tl, troot);
    bucket_csr_kernel<<<NBUCK, 256, 0, stream>>>(scat, gbb, prow, deg, peidx, perm);

    agg_kernel<false><<<AGG_GRID, 256, 0, stream>>>(tl, troot, prow, deg, peidx, perm,
                                                    bnsc, bnsh, nullptr, nullptr, h, nullptr);
    gemm_kernel<HID, false><<<GEMM_GRID, 256, 0, stream>>>(h, Bf1, tl, troot);
    agg_kernel<false><<<AGG_GRID, 256, 0, stream>>>(tl, troot, prow, deg, peidx, perm,
                                                    bnsc + HID, bnsh + HID, nullptr, nullptr, h, nullptr);
    gemm_kernel<HID, false><<<GEMM_GRID, 256, 0, stream>>>(h, Bf2, tl, troot);
    agg_kernel<true><<<AGG_GRID, 256, 0, stream>>>(tl, troot, prow, deg, peidx, perm,
                                                   bnsc + 2 * HID, bnsh + 2 * HID,
                                                   lin_w, lin_b, nullptr, out);
}

// Round 2
// 435.064 us; speedup vs baseline: 1.0671x; 1.0175x over previous
//
#include <hip/hip_runtime.h>

#define N_NODES 100000
#define N_EDGES 1600000
#define IN_DIM 160
#define HID 128
#define BN_EPS 1e-5f

#define M_PAD 100096   // 1564 * 64 rows (GEMM block = 64 rows)
#define NBUCK 196      // 512-node buckets (196*512 = 100352 >= N_NODES)
#define BSH 9
#define EPB 8192       // edges per block in hist/scatter kernels
#define NHB (NBUCK * NBUCK)   // 38416, divisible by 4
#define NSB 38         // scan blocks: 38*1024 = 38912 >= NHB
#define LPAD 132       // gemm LDS repack row stride (ushorts)

typedef unsigned int uint;
typedef unsigned short ushort;
typedef __attribute__((ext_vector_type(8))) short bf16x8;
typedef __attribute__((ext_vector_type(4))) float f32x4;
typedef __attribute__((ext_vector_type(2))) float f32x2;

__device__ __forceinline__ ushort bf16rn(float f) {
    uint u = __float_as_uint(f);
    u += 0x7fffu + ((u >> 16) & 1u);
    return (ushort)(u >> 16);
}
__device__ __forceinline__ float bflo(uint u) { return __uint_as_float(u << 16); }
__device__ __forceinline__ float bfhi(uint u) { return __uint_as_float(u & 0xffff0000u); }

// ---------------------------------------------------------------------------
// Fused init: hist (196 blocks) + weight prep (52 blocks) + bn prep (2).
// ---------------------------------------------------------------------------

__device__ __forceinline__ void prep_body(int ob, int lane, const float* __restrict__ wl,
                                          const float* __restrict__ wr,
                                          ushort* __restrict__ Bf, int K) {
    int kb = ob >> 4;       // K-step (32 wide)
    int tt = ob & 15;       // col tile
    int n = tt * 16 + (lane & 15);
    int k0 = kb * 32 + (lane >> 4) * 8;
    ushort* dst = Bf + ((size_t)(kb * 16 + tt) * 64 + lane) * 8;
#pragma unroll
    for (int e = 0; e < 8; ++e) {
        int k = k0 + e;
        float v = (n < HID) ? wl[k * HID + n] : wr[k * HID + (n - HID)];
        dst[e] = bf16rn(v);
    }
}

#define PREP0_B 20   // (IN_DIM/32)*16 = 80 old 64-thread blocks / 4
#define PREP1_B 16   // (HID/32)*16   = 64 old 64-thread blocks / 4
#define INIT_GRID (NBUCK + PREP0_B + 2 * PREP1_B + 2)

__global__ __launch_bounds__(256) void init_kernel(
    const int* __restrict__ dst, int* __restrict__ ghist,
    const float* __restrict__ wl0, const float* __restrict__ wr0,
    const float* __restrict__ wl1, const float* __restrict__ wr1,
    const float* __restrict__ wl2, const float* __restrict__ wr2,
    ushort* __restrict__ Bf0, ushort* __restrict__ Bf1, ushort* __restrict__ Bf2,
    const float* __restrict__ bl0, const float* __restrict__ g0,
    const float* __restrict__ be0, const float* __restrict__ rm0,
    const float* __restrict__ rv0,
    const float* __restrict__ bl1, const float* __restrict__ g1,
    const float* __restrict__ be1, const float* __restrict__ rm1,
    const float* __restrict__ rv1,
    const float* __restrict__ bl2, const float* __restrict__ g2,
    const float* __restrict__ be2, const float* __restrict__ rm2,
    const float* __restrict__ rv2,
    float* __restrict__ bnscale, float* __restrict__ bnshift) {
    __shared__ int hist[NBUCK];
    int b = blockIdx.x, t = threadIdx.x;
    if (b < NBUCK) {
        for (int i = t; i < NBUCK; i += 256) hist[i] = 0;
        __syncthreads();
        int e0 = b * EPB;
        for (int i = 0; i < EPB; i += 256) {
            int e = e0 + i + t;
            if (e < N_EDGES) atomicAdd(&hist[dst[e] >> BSH], 1);
        }
        __syncthreads();
        for (int i = t; i < NBUCK; i += 256) ghist[i * NBUCK + b] = hist[i];
    } else if (b < NBUCK + PREP0_B) {
        int ob = (b - NBUCK) * 4 + (t >> 6);
        prep_body(ob, t & 63, wl0, wr0, Bf0, IN_DIM);
    } else if (b < NBUCK + PREP0_B + PREP1_B) {
        int ob = (b - NBUCK - PREP0_B) * 4 + (t >> 6);
        prep_body(ob, t & 63, wl1, wr1, Bf1, HID);
    } else if (b < NBUCK + PREP0_B + 2 * PREP1_B) {
        int ob = (b - NBUCK - PREP0_B - PREP1_B) * 4 + (t >> 6);
        prep_body(ob, t & 63, wl2, wr2, Bf2, HID);
    } else {
        int tt = (b - (NBUCK + PREP0_B + 2 * PREP1_B)) * 256 + t;
        if (tt < 3 * HID) {
            int L = tt >> 7, j = tt & 127;
            const float* bl = (L == 0) ? bl0 : (L == 1) ? bl1 : bl2;
            const float* gg = (L == 0) ? g0  : (L == 1) ? g1  : g2;
            const float* be = (L == 0) ? be0 : (L == 1) ? be1 : be2;
            const float* rm = (L == 0) ? rm0 : (L == 1) ? rm1 : rm2;
            const float* rv = (L == 0) ? rv0 : (L == 1) ? rv1 : rv2;
            float s = gg[j] * rsqrtf(rv[j] + BN_EPS);
            bnscale[tt] = s;
            bnshift[tt] = (bl[j] - rm[j]) * s + be[j];
        }
    }
}

// ---------------------------------------------------------------------------
// Scan chain (unchanged)
// ---------------------------------------------------------------------------

__global__ __launch_bounds__(256) void scan1_kernel(const int* __restrict__ ghist,
                                                    int* __restrict__ bsum) {
    __shared__ int wsum[4];
    int b = blockIdx.x, t = threadIdx.x;
    int i4 = b * 256 + t;
    int4 v = (i4 * 4 < NHB) ? ((const int4*)ghist)[i4] : make_int4(0, 0, 0, 0);
    int s = v.x + v.y + v.z + v.w;
#pragma unroll
    for (int off = 32; off; off >>= 1) s += __shfl_down(s, off);
    if ((t & 63) == 0) wsum[t >> 6] = s;
    __syncthreads();
    if (t == 0) bsum[b] = wsum[0] + wsum[1] + wsum[2] + wsum[3];
}

__global__ void scan2_kernel(const int* __restrict__ bsum, int* __restrict__ boff,
                             int* __restrict__ gbb) {
    int lane = threadIdx.x;
    int v = (lane < NSB) ? bsum[lane] : 0;
    int s = v;
#pragma unroll
    for (int off = 1; off <= 32; off <<= 1) {
        int t2 = __shfl_up(s, off);
        if (lane >= off) s += t2;
    }
    if (lane < NSB) boff[lane] = s - v;
    if (lane == 0) gbb[NBUCK] = N_EDGES;
}

__global__ __launch_bounds__(256) void scan3_kernel(int* __restrict__ ghist,
                                                    const int* __restrict__ boff,
                                                    int* __restrict__ gbb) {
    __shared__ int ts[256];
    int b = blockIdx.x, t = threadIdx.x;
    int i4 = b * 256 + t;
    bool ok = (i4 * 4) < NHB;
    int4 v = ok ? ((const int4*)ghist)[i4] : make_int4(0, 0, 0, 0);
    int s = v.x + v.y + v.z + v.w;
    ts[t] = s;
    __syncthreads();
    for (int off = 1; off < 256; off <<= 1) {
        int a = (t >= off) ? ts[t - off] : 0;
        __syncthreads();
        ts[t] += a;
        __syncthreads();
    }
    int excl = boff[b] + ((t > 0) ? ts[t - 1] : 0);
    if (ok) {
        int idx = i4 * 4;
        int4 w;
        w.x = excl;
        w.y = excl + v.x;
        w.z = excl + v.x + v.y;
        w.w = excl + v.x + v.y + v.z;
        ((int4*)ghist)[i4] = w;
        if (idx % NBUCK == 0) gbb[idx / NBUCK] = w.x;
    }
}

// ---------------------------------------------------------------------------
// Bucket CSR -> padded per-node edge lists (round-0 version, no perm)
// ---------------------------------------------------------------------------

__global__ __launch_bounds__(256) void bucket_csr_kernel(const uint* __restrict__ scat,
                                                         const int* __restrict__ gbb,
                                                         int* __restrict__ prow,
                                                         int* __restrict__ deg,
                                                         int* __restrict__ peidx) {
    __shared__ int cnt[512], fl[512], pref[512];
    __shared__ int ts[256];
    __shared__ int tot_s;
    int b = blockIdx.x, t = threadIdx.x;
    int beg = gbb[b], end = gbb[b + 1];
    int pb = beg + b * 8192;
    cnt[t] = 0; cnt[t + 256] = 0;
    __syncthreads();
    for (int i = beg + t; i < end; i += 256)
        atomicAdd(&cnt[scat[i] >> 17], 1);
    __syncthreads();
    int c0 = cnt[2 * t], c1 = cnt[2 * t + 1];
    int p0 = (c0 + 15) & ~15, p1 = (c1 + 15) & ~15;
    ts[t] = p0 + p1;
    __syncthreads();
    for (int off = 1; off < 256; off <<= 1) {
        int v = (t >= off) ? ts[t - off] : 0;
        __syncthreads();
        ts[t] += v;
        __syncthreads();
    }
    int ex = (t > 0) ? ts[t - 1] : 0;
    pref[2 * t] = ex;
    pref[2 * t + 1] = ex + p0;
    fl[t] = 0; fl[t + 256] = 0;
    if (t == 255) tot_s = ts[255];
    int g0 = b * 512 + 2 * t;
    if (g0 < N_NODES) { prow[g0] = pb + ex; deg[g0] = c0; }
    if (g0 + 1 < N_NODES) { prow[g0 + 1] = pb + ex + p0; deg[g0 + 1] = c1; }
    __syncthreads();
    int tot = tot_s;
    for (int i = t; i < tot; i += 256) peidx[pb + i] = N_NODES;  // pad -> zero row
    __syncthreads();
    for (int i = beg + t; i < end; i += 256) {
        uint w = scat[i];
        int nl = (int)(w >> 17);
        int lp = atomicAdd(&fl[nl], 1);
        peidx[pb + pref[nl] + lp] = (int)(w & 0x1FFFFu);
    }
}

// ---------------------------------------------------------------------------
// GEMM body: [tl | troot] = A @ [wl | wr]. Block = 64 rows x 256 cols.
// ---------------------------------------------------------------------------
template <int K, bool AFP32>
__device__ __forceinline__ void gemm_body(int bx, int t, ushort* ldsA,
                                          const void* __restrict__ A_,
                                          const ushort* __restrict__ Bf,
                                          ushort* __restrict__ tl,
                                          ushort* __restrict__ troot) {
    constexpr int CPR = K / 8;                 // 16B chunks per row
    constexpr int FULLG = CPR & ~7;            // start of partial swizzle group
    const int m0b = bx * 64;

    // ---- Stage A tile (64 rows x K) ----
#pragma unroll
    for (int i = 0; i < (64 * CPR) / 256; ++i) {
        int cidx = i * 256 + t;
        int row = cidx / CPR;
        int j = cidx - row * CPR;
        bf16x8 v;
        if (AFP32) {
            const float* A = (const float*)A_;
            int m = m0b + row;
            float4 f0 = make_float4(0.f, 0.f, 0.f, 0.f), f1 = f0;
            if (m < N_NODES) {
                f0 = *(const float4*)(A + (size_t)m * K + j * 8);
                f1 = *(const float4*)(A + (size_t)m * K + j * 8 + 4);
            }
            v[0] = (short)bf16rn(f0.x); v[1] = (short)bf16rn(f0.y);
            v[2] = (short)bf16rn(f0.z); v[3] = (short)bf16rn(f0.w);
            v[4] = (short)bf16rn(f1.x); v[5] = (short)bf16rn(f1.y);
            v[6] = (short)bf16rn(f1.z); v[7] = (short)bf16rn(f1.w);
        } else {
            const ushort* A = (const ushort*)A_;
            v = *(const bf16x8*)(A + (size_t)(m0b + row) * K + j * 8);
        }
        int swz = (j < FULLG) ? ((j & ~7) | ((j ^ row) & 7))
                              : ((j & ~3) | ((j ^ row) & 3));
        *(bf16x8*)&ldsA[row * K + swz * 8] = v;
    }
    __syncthreads();

    // ---- K-loop ----
    const int lane = t & 63;
    const int wv = t >> 6;
    const int col = lane & 15;
    const int q = lane >> 4;
    const int rh = wv & 1;
    const int ch = wv >> 1;
    const int row0 = rh * 32 + col;            // row0 & 7 == col & 7
    f32x4 acc0[8], acc1[8];
#pragma unroll
    for (int tt = 0; tt < 8; ++tt) {
        acc0[tt] = (f32x4){0.f, 0.f, 0.f, 0.f};
        acc1[tt] = (f32x4){0.f, 0.f, 0.f, 0.f};
    }

#pragma unroll
    for (int kb = 0; kb < K / 32; ++kb) {
        int jj = kb * 4 + q;
        int swzj = (jj < FULLG) ? ((jj & ~7) | ((jj ^ col) & 7))
                                : ((jj & ~3) | ((jj ^ col) & 3));
        bf16x8 a0 = *(const bf16x8*)&ldsA[row0 * K + swzj * 8];
        bf16x8 a1 = *(const bf16x8*)&ldsA[(row0 + 16) * K + swzj * 8];
        const ushort* bp = Bf + ((size_t)((kb * 16 + ch * 8) * 64) + lane) * 8;
#pragma unroll
        for (int tt = 0; tt < 8; ++tt) {
            bf16x8 bfr = *(const bf16x8*)(bp + (size_t)tt * 64 * 8);
            acc0[tt] = __builtin_amdgcn_mfma_f32_16x16x32_bf16(a0, bfr, acc0[tt], 0, 0, 0);
            acc1[tt] = __builtin_amdgcn_mfma_f32_16x16x32_bf16(a1, bfr, acc1[tt], 0, 0, 0);
        }
    }

    // ---- Epilogue: per-wave LDS repack (128 cols), coalesced 256B stores ----
    __syncthreads();   // all waves done reading A region before aliasing
    ushort(*rp)[16][LPAD] = (ushort(*)[16][LPAD])ldsA;
    ushort* outp = ch ? troot : tl;
#pragma unroll
    for (int mt = 0; mt < 2; ++mt) {
        const f32x4* ac = mt ? acc1 : acc0;
#pragma unroll
        for (int tt = 0; tt < 8; ++tt)
#pragma unroll
            for (int r = 0; r < 4; ++r)
                rp[wv][q * 4 + r][tt * 16 + col] = bf16rn(ac[tt][r]);
        int mbase = m0b + rh * 32 + mt * 16;
#pragma unroll
        for (int i = 0; i < 4; ++i) {
            int lin = i * 64 + lane;
            int row = lin >> 4;      // 4 rows per instr (16 lanes x 16B)
            int c16 = lin & 15;
            bf16x8 v = *(const bf16x8*)&rp[wv][row][c16 * 8];
            *(bf16x8*)(outp + (size_t)(mbase + row) * HID + c16 * 8) = v;
        }
    }
}

// ---------------------------------------------------------------------------
// Fused scatter (196 latency-bound blocks) + layer-0 GEMM (1564 compute blocks).
// ---------------------------------------------------------------------------
__global__ __launch_bounds__(256) void scatter_gemm1_kernel(
    const int* __restrict__ src, const int* __restrict__ dst,
    const int* __restrict__ ghist, uint* __restrict__ scat,
    const float* __restrict__ x, const ushort* __restrict__ Bf0,
    ushort* __restrict__ tl, ushort* __restrict__ troot) {
    constexpr int LDSE = (64 * IN_DIM > 4 * 16 * LPAD) ? 64 * IN_DIM : 4 * 16 * LPAD;
    __shared__ ushort ldsA[LDSE];
    int b = blockIdx.x, t = threadIdx.x;
    if (b < NBUCK) {
        int* base = (int*)ldsA;
        int* fill = base + NBUCK;
        for (int i = t; i < NBUCK; i += 256) { base[i] = ghist[i * NBUCK + b]; fill[i] = 0; }
        __syncthreads();
        int e0 = b * EPB;
        for (int i = 0; i < EPB; i += 256) {
            int e = e0 + i + t;
            if (e < N_EDGES) {
                int d = dst[e];
                int sv = src[e];
                int bk = d >> BSH;
                int lp = atomicAdd(&fill[bk], 1);
                scat[base[bk] + lp] = (uint)sv | ((uint)(d & 511) << 17);
            }
        }
    } else {
        gemm_body<IN_DIM, true>(b - NBUCK, t, ldsA, x, Bf0, tl, troot);
    }
}

// ---------------------------------------------------------------------------
// Fused agg_k + gemm_{k+1}: block = 64-node tile. Phase 1 aggregates its own
// 64 nodes (gather from tl_in/troot_in, BN+ReLU) writing bf16 rows DIRECTLY
// into the swizzled LDS A-tile (h round-trip eliminated). Phase 2 = MFMA
// K-loop + epilogue -> tl_out/troot_out (ping-pong buffers vs tl_in).
// Fetch-bound (agg) and MFMA-bound (gemm) blocks co-schedule across CUs,
// hiding the GEMM inside agg's saturated ~3.6 TB/s fetch-path time.
// ---------------------------------------------------------------------------
__global__ __launch_bounds__(256) void fused_agg_gemm_kernel(
    const ushort* __restrict__ tl_in, const ushort* __restrict__ troot_in,
    const int* __restrict__ prow, const int* __restrict__ deg_,
    const int* __restrict__ peidx,
    const float* __restrict__ bnscale, const float* __restrict__ bnshift,
    const ushort* __restrict__ Bf,
    ushort* __restrict__ tl_out, ushort* __restrict__ troot_out) {
    constexpr int K = HID;
    constexpr int LDSE = (64 * K > 4 * 16 * LPAD) ? 64 * K : 4 * 16 * LPAD;
    __shared__ ushort ldsA[LDSE];
    const int t = threadIdx.x;
    const int lane = t & 63;
    const int wv = t >> 6;
    const int m0b = blockIdx.x * 64;
    const int g = lane >> 4;          // node group within wave
    const int s = lane & 15;          // feat slice: feats s*8 .. s*8+7
    const int gsel = (lane & 48) << 2;

    // ---- Phase 1: aggregate 64 nodes (4 rounds x 4 waves x 4 nodes) ----
    for (int r = 0; r < 4; ++r) {
        const int row = wv * 16 + r * 4 + g;
        const int n = m0b + row;
        const bool valid = (n < N_NODES);
        const int nn = valid ? n : 0;
        int pbeg = prow[nn];
        int dg = valid ? deg_[nn] : 0;
        int myb = (dg + 15) >> 4;

        f32x2 acc2[4];
#pragma unroll
        for (int i = 0; i < 4; ++i) acc2[i] = (f32x2){0.f, 0.f};

        bool act = (0 < myb);
        int idx = act ? peidx[pbeg + s] : N_NODES;
        int b = 0;
        while (__any(act)) {
            uint4 u[16];
#pragma unroll
            for (int jj = 0; jj < 16; ++jj) {
                int srcj = __builtin_amdgcn_ds_bpermute(gsel | (jj << 2), idx);
                u[jj] = *(const uint4*)(tl_in + (size_t)srcj * HID + s * 8);
            }
            ++b;
            bool actn = (b < myb);
            int idxn = actn ? peidx[pbeg + b * 16 + s] : N_NODES;  // prefetch next batch
#pragma unroll
            for (int jj = 0; jj < 16; ++jj) {
                acc2[0] += (f32x2){bflo(u[jj].x), bfhi(u[jj].x)};
                acc2[1] += (f32x2){bflo(u[jj].y), bfhi(u[jj].y)};
                acc2[2] += (f32x2){bflo(u[jj].z), bfhi(u[jj].z)};
                acc2[3] += (f32x2){bflo(u[jj].w), bfhi(u[jj].w)};
            }
            act = actn; idx = idxn;
        }

        float inv = 1.0f / (float)((dg > 0) ? dg : 1);
        uint4 rv = *(const uint4*)(troot_in + (size_t)nn * HID + s * 8);
        float4 sc0 = *(const float4*)(bnscale + s * 8);
        float4 sc1 = *(const float4*)(bnscale + s * 8 + 4);
        float4 sh0 = *(const float4*)(bnshift + s * 8);
        float4 sh1 = *(const float4*)(bnshift + s * 8 + 4);
        float vm = valid ? 1.0f : 0.0f;
        float o[8];
        o[0] = fmaxf(fmaf(fmaf(acc2[0].x, inv, bflo(rv.x)), sc0.x, sh0.x), 0.f) * vm;
        o[1] = fmaxf(fmaf(fmaf(acc2[0].y, inv, bfhi(rv.x)), sc0.y, sh0.y), 0.f) * vm;
        o[2] = fmaxf(fmaf(fmaf(acc2[1].x, inv, bflo(rv.y)), sc0.z, sh0.z), 0.f) * vm;
        o[3] = fmaxf(fmaf(fmaf(acc2[1].y, inv, bfhi(rv.y)), sc0.w, sh0.w), 0.f) * vm;
        o[4] = fmaxf(fmaf(fmaf(acc2[2].x, inv, bflo(rv.z)), sc1.x, sh1.x), 0.f) * vm;
        o[5] = fmaxf(fmaf(fmaf(acc2[2].y, inv, bfhi(rv.z)), sc1.y, sh1.y), 0.f) * vm;
        o[6] = fmaxf(fmaf(fmaf(acc2[3].x, inv, bflo(rv.w)), sc1.z, sh1.z), 0.f) * vm;
        o[7] = fmaxf(fmaf(fmaf(acc2[3].y, inv, bfhi(rv.w)), sc1.w, sh1.w), 0.f) * vm;

        bf16x8 pk;
#pragma unroll
        for (int e = 0; e < 8; ++e) pk[e] = (short)bf16rn(o[e]);
        // same swizzle as gemm staging: K=128 -> full 8-groups everywhere
        int swz = (s & ~7) | ((s ^ row) & 7);
        *(bf16x8*)&ldsA[row * K + swz * 8] = pk;
    }
    __syncthreads();

    // ---- Phase 2: GEMM K-loop (identical to gemm_body post-staging) ----
    const int col = lane & 15;
    const int q = lane >> 4;
    const int rh = wv & 1;
    const int ch = wv >> 1;
    const int row0 = rh * 32 + col;
    f32x4 acc0[8], acc1[8];
#pragma unroll
    for (int tt = 0; tt < 8; ++tt) {
        acc0[tt] = (f32x4){0.f, 0.f, 0.f, 0.f};
        acc1[tt] = (f32x4){0.f, 0.f, 0.f, 0.f};
    }
#pragma unroll
    for (int kb = 0; kb < K / 32; ++kb) {
        int jj = kb * 4 + q;
        int swzj = (jj & ~7) | ((jj ^ col) & 7);
        bf16x8 a0 = *(const bf16x8*)&ldsA[row0 * K + swzj * 8];
        bf16x8 a1 = *(const bf16x8*)&ldsA[(row0 + 16) * K + swzj * 8];
        const ushort* bp = Bf + ((size_t)((kb * 16 + ch * 8) * 64) + lane) * 8;
#pragma unroll
        for (int tt = 0; tt < 8; ++tt) {
            bf16x8 bfr = *(const bf16x8*)(bp + (size_t)tt * 64 * 8);
            acc0[tt] = __builtin_amdgcn_mfma_f32_16x16x32_bf16(a0, bfr, acc0[tt], 0, 0, 0);
            acc1[tt] = __builtin_amdgcn_mfma_f32_16x16x32_bf16(a1, bfr, acc1[tt], 0, 0, 0);
        }
    }

    __syncthreads();   // all waves done reading A region before aliasing
    ushort(*rp)[16][LPAD] = (ushort(*)[16][LPAD])ldsA;
    ushort* outp = ch ? troot_out : tl_out;
#pragma unroll
    for (int mt = 0; mt < 2; ++mt) {
        const f32x4* ac = mt ? acc1 : acc0;
#pragma unroll
        for (int tt = 0; tt < 8; ++tt)
#pragma unroll
            for (int rr = 0; rr < 4; ++rr)
                rp[wv][q * 4 + rr][tt * 16 + col] = bf16rn(ac[tt][rr]);
        int mbase = m0b + rh * 32 + mt * 16;
#pragma unroll
        for (int i = 0; i < 4; ++i) {
            int lin = i * 64 + lane;
            int rowi = lin >> 4;
            int c16 = lin & 15;
            bf16x8 v = *(const bf16x8*)&rp[wv][rowi][c16 * 8];
            *(bf16x8*)(outp + (size_t)(mbase + rowi) * HID + c16 * 8) = v;
        }
    }
}

// ---------------------------------------------------------------------------
// Final aggregation + BN + ReLU + linear head (natural node order, round-0
// structure: 60 VGPR, high occupancy on the saturated fetch path).
// ---------------------------------------------------------------------------
__global__ __launch_bounds__(256) void agg_final_kernel(
    const ushort* __restrict__ tl_, const ushort* __restrict__ troot_,
    const int* __restrict__ prow, const int* __restrict__ deg_,
    const int* __restrict__ peidx,
    const float* __restrict__ bnscale, const float* __restrict__ bnshift,
    const float* __restrict__ linw, const float* __restrict__ linb,
    float* __restrict__ out) {
    const int lane = threadIdx.x & 63;
    const int wvg = (blockIdx.x * 256 + (int)threadIdx.x) >> 6;
    const int g = lane >> 4;
    const int s = lane & 15;
    const int n = wvg * 4 + g;        // grid covers exactly N_NODES

    int pbeg = prow[n];
    int dg = deg_[n];
    int myb = (dg + 15) >> 4;

    f32x2 acc2[4];
#pragma unroll
    for (int i = 0; i < 4; ++i) acc2[i] = (f32x2){0.f, 0.f};

    const int gsel = (lane & 48) << 2;

    bool act = (0 < myb);
    int idx = act ? peidx[pbeg + s] : N_NODES;
    int b = 0;
    while (__any(act)) {
        uint4 u[16];
#pragma unroll
        for (int jj = 0; jj < 16; ++jj) {
            int srcj = __builtin_amdgcn_ds_bpermute(gsel | (jj << 2), idx);
            u[jj] = *(const uint4*)(tl_ + (size_t)srcj * HID + s * 8);
        }
        ++b;
        bool actn = (b < myb);
        int idxn = actn ? peidx[pbeg + b * 16 + s] : N_NODES;
#pragma unroll
        for (int jj = 0; jj < 16; ++jj) {
            acc2[0] += (f32x2){bflo(u[jj].x), bfhi(u[jj].x)};
            acc2[1] += (f32x2){bflo(u[jj].y), bfhi(u[jj].y)};
            acc2[2] += (f32x2){bflo(u[jj].z), bfhi(u[jj].z)};
            acc2[3] += (f32x2){bflo(u[jj].w), bfhi(u[jj].w)};
        }
        act = actn; idx = idxn;
    }

    float inv = 1.0f / (float)((dg > 0) ? dg : 1);
    uint4 rv = *(const uint4*)(troot_ + (size_t)n * HID + s * 8);
    float4 sc0 = *(const float4*)(bnscale + s * 8);
    float4 sc1 = *(const float4*)(bnscale + s * 8 + 4);
    float4 sh0 = *(const float4*)(bnshift + s * 8);
    float4 sh1 = *(const float4*)(bnshift + s * 8 + 4);
    float o[8];
    o[0] = fmaxf(fmaf(fmaf(acc2[0].x, inv, bflo(rv.x)), sc0.x, sh0.x), 0.f);
    o[1] = fmaxf(fmaf(fmaf(acc2[0].y, inv, bfhi(rv.x)), sc0.y, sh0.y), 0.f);
    o[2] = fmaxf(fmaf(fmaf(acc2[1].x, inv, bflo(rv.y)), sc0.z, sh0.z), 0.f);
    o[3] = fmaxf(fmaf(fmaf(acc2[1].y, inv, bfhi(rv.y)), sc0.w, sh0.w), 0.f);
    o[4] = fmaxf(fmaf(fmaf(acc2[2].x, inv, bflo(rv.z)), sc1.x, sh1.x), 0.f);
    o[5] = fmaxf(fmaf(fmaf(acc2[2].y, inv, bfhi(rv.z)), sc1.y, sh1.y), 0.f);
    o[6] = fmaxf(fmaf(fmaf(acc2[3].x, inv, bflo(rv.w)), sc1.z, sh1.z), 0.f);
    o[7] = fmaxf(fmaf(fmaf(acc2[3].y, inv, bfhi(rv.w)), sc1.w, sh1.w), 0.f);

    float4 w0 = *(const float4*)(linw + s * 8);
    float4 w1 = *(const float4*)(linw + s * 8 + 4);
    float p = o[0] * w0.x + o[1] * w0.y + o[2] * w0.z + o[3] * w0.w +
              o[4] * w1.x + o[5] * w1.y + o[6] * w1.z + o[7] * w1.w;
#pragma unroll
    for (int off = 1; off < 16; off <<= 1) p += __shfl_xor(p, off);
    if (s == 0) out[n] = p + linb[0];
}

// ---------------------------------------------------------------------------

extern "C" void kernel_launch(void* const* d_in, const int* in_sizes, int n_in,
                              void* d_out, int out_size, void* d_ws, size_t ws_size,
                              hipStream_t stream) {
    const float* x    = (const float*)d_in[0];
    const int*   ei   = (const int*)d_in[1];
    const int*   esrc = ei;
    const int*   edst = ei + N_EDGES;
    const float* wl[3]; const float* wr[3]; const float* bl[3];
    const float* g[3];  const float* be[3]; const float* rm[3]; const float* rv[3];
    for (int i = 0; i < 3; ++i) {
        wl[i] = (const float*)d_in[2 + 7 * i];
        wr[i] = (const float*)d_in[3 + 7 * i];
        bl[i] = (const float*)d_in[4 + 7 * i];
        g[i]  = (const float*)d_in[5 + 7 * i];
        be[i] = (const float*)d_in[6 + 7 * i];
        rm[i] = (const float*)d_in[7 + 7 * i];
        rv[i] = (const float*)d_in[8 + 7 * i];
    }
    const float* lin_w = (const float*)d_in[23];
    const float* lin_b = (const float*)d_in[24];
    float* out = (float*)d_out;

    // Workspace carve-up (~123 MB total; h buffer dropped, tl/troot ping-pong added).
    char* ws = (char*)d_ws;
    size_t off = 0;
    auto carve = [&](size_t bytes) -> void* {
        void* p = ws + off;
        off += (bytes + 255) & ~(size_t)255;
        return p;
    };
    int*    prow   = (int*)carve((size_t)(N_NODES + 8) * sizeof(int));
    int*    deg    = (int*)carve((size_t)(N_NODES + 8) * sizeof(int));
    int*    peidx  = (int*)carve((size_t)3210000 * sizeof(int));   // padded CSR
    uint*   scat   = (uint*)carve((size_t)N_EDGES * sizeof(uint));
    int*    ghist  = (int*)carve((size_t)(NSB * 1024) * sizeof(int));
    int*    gbb    = (int*)carve((NBUCK + 4) * sizeof(int));
    int*    bsum   = (int*)carve((NSB + 2) * sizeof(int));
    int*    boff   = (int*)carve((NSB + 2) * sizeof(int));
    ushort* tl0    = (ushort*)carve((size_t)(M_PAD + 1) * HID * sizeof(ushort));
    ushort* troot0 = (ushort*)carve((size_t)M_PAD * HID * sizeof(ushort));
    ushort* tl1    = (ushort*)carve((size_t)(M_PAD + 1) * HID * sizeof(ushort));
    ushort* troot1 = (ushort*)carve((size_t)M_PAD * HID * sizeof(ushort));
    ushort* Bf0    = (ushort*)carve(256 * IN_DIM * sizeof(ushort));
    ushort* Bf1    = (ushort*)carve(256 * HID * sizeof(ushort));
    ushort* Bf2    = (ushort*)carve(256 * HID * sizeof(ushort));
    float*  bnsc   = (float*)carve(3 * HID * sizeof(float));
    float*  bnsh   = (float*)carve(3 * HID * sizeof(float));
    (void)ws_size; (void)n_in; (void)in_sizes; (void)out_size;

    const int GEMM_GRID = M_PAD / 64;           // 1564 blocks, 64 rows x 256 cols
    const int AGGF_GRID = N_NODES / 16;         // 6250 blocks, 16 nodes each

    init_kernel<<<INIT_GRID, 256, 0, stream>>>(
        edst, ghist,
        wl[0], wr[0], wl[1], wr[1], wl[2], wr[2], Bf0, Bf1, Bf2,
        bl[0], g[0], be[0], rm[0], rv[0],
        bl[1], g[1], be[1], rm[1], rv[1],
        bl[2], g[2], be[2], rm[2], rv[2],
        bnsc, bnsh);
    scan1_kernel<<<NSB, 256, 0, stream>>>(ghist, bsum);
    scan2_kernel<<<1, 64, 0, stream>>>(bsum, boff, gbb);
    scan3_kernel<<<NSB, 256, 0, stream>>>(ghist, boff, gbb);
    scatter_gemm1_kernel<<<NBUCK + GEMM_GRID, 256, 0, stream>>>(
        esrc, edst, ghist, scat, x, Bf0, tl0, troot0);
    bucket_csr_kernel<<<NBUCK, 256, 0, stream>>>(scat, gbb, prow, deg, peidx);

    // layer 1: agg(tl0) + gemm(Bf1) -> tl1 ; layer 2: agg(tl1) + gemm(Bf2) -> tl0
    fused_agg_gemm_kernel<<<GEMM_GRID, 256, 0, stream>>>(
        tl0, troot0, prow, deg, peidx, bnsc, bnsh, Bf1, tl1, troot1);
    fused_agg_gemm_kernel<<<GEMM_GRID, 256, 0, stream>>>(
        tl1, troot1, prow, deg, peidx, bnsc + HID, bnsh + HID, Bf2, tl0, troot0);
    agg_final_kernel<<<AGGF_GRID, 256, 0, stream>>>(
        tl0, troot0, prow, deg, peidx, bnsc + 2 * HID, bnsh + 2 * HID,
        lin_w, lin_b, out);
}